// Round 6
// baseline (215.127 us; speedup 1.0000x reference)
//
#include <hip/hip_runtime.h>

// Problem constants
#define D 32
#define K 8
#define NPAIR 36
#define PROWS 576              // packed (4-padded triangular) floats per matrix

// ws layout (float offsets)
#define PMOFF 0                // packed invLc, 8 x 576
#define WOFF 4608              // w_k = invLc_k mu_k, 8 x 32
#define C2OFF 4864             // (c'_t - cmax) * log2(e), 36
#define CMAXOFF 4900
#define LCOFF 4928             // Lc (cholesky factors), 8 x 32 x 32, upper zeroed
#define PARTOFF 13120          // per-block partial sums (<=1024)

typedef float v2f __attribute__((ext_vector_type(2)));

__host__ __device__ constexpr int gidx(int i, int j) {  // i<=j packed pair index
    return i * 8 + j - i * (i + 1) / 2;
}
__host__ __device__ constexpr int proff(int r) {        // packed row offset
    return 4 * (r / 4 + 1) * (2 * (r / 4) + (r % 4));
}

// ---------------------------------------------------------------------------
// setup1 (unchanged from round 5 -- verified fast): one 64-thread block per
// cluster. At most one 32-float register array live per phase (no spills).
// ---------------------------------------------------------------------------
__global__ __launch_bounds__(64) void setup1_kernel(
    const float* __restrict__ mu, const float* __restrict__ L,
    float* __restrict__ ws)
{
    __shared__ float sL[D][D + 1];    // L rows; reused later for invLc
    __shared__ float sLc[D][D + 1];   // published Cholesky rows
    const int k = blockIdx.x;
    const int tid = threadIdx.x;
    const int i = tid & 31;

    for (int e = tid; e < D * D; e += 64) sL[e >> 5][e & 31] = L[k * D * D + e];
    __syncthreads();

    // Phase A: a[c] = <L_i, L_c> + (i==c)
    float a[D];
    {
        float l[D];
        #pragma unroll
        for (int b = 0; b < D; ++b) l[b] = sL[i][b];
        #pragma unroll
        for (int c = 0; c < D; ++c) {
            float s = (i == c) ? 1.0f : 0.0f;
            #pragma unroll
            for (int b = 0; b < D; ++b) s = fmaf(l[b], sL[c][b], s);
            a[c] = s;
        }
    }
    __syncthreads();

    // Phase B: left-looking Cholesky in place (a[j] -> Lc[i][j])
    #pragma unroll
    for (int j = 0; j < D; ++j) {
        if (i == j) {
            float s = a[j];
            #pragma unroll
            for (int b = 0; b < j; ++b) s = fmaf(-a[b], a[b], s);
            const float d = sqrtf(s);
            a[j] = d;
            #pragma unroll
            for (int b = 0; b < j; ++b) sLc[j][b] = a[b];
            sLc[j][j] = d;
        }
        __syncthreads();
        if (i > j) {
            float s = a[j];
            #pragma unroll
            for (int b = 0; b < j; ++b) s = fmaf(-a[b], sLc[j][b], s);
            a[j] = s / sLc[j][j];
        }
    }
    __syncthreads();

    // Lc rows to ws for setup2
    for (int e = tid; e < D * D; e += 64) {
        const int r = e >> 5, c = e & 31;
        ws[LCOFF + k * D * D + e] = (c <= r) ? sLc[r][c] : 0.0f;
    }

    // Phase C: invLc column i (col[ii]=0 for ii<i by induction)
    float col[D];
    #pragma unroll
    for (int ii = 0; ii < D; ++ii) {
        float s = (ii == i) ? 1.0f : 0.0f;
        #pragma unroll
        for (int b = 0; b < ii; ++b) {
            const float m = (b >= i) ? sLc[ii][b] : 0.0f;
            s = fmaf(-m, col[b], s);
        }
        col[ii] = s / sLc[ii][ii];
    }

    // Packed M store (row ii at proff(ii), width 4*(ii/4+1); zero pad implicit)
    #pragma unroll
    for (int ii = 0; ii < D; ++ii) {
        const int w4 = 4 * (ii / 4 + 1);
        if (i < w4) ws[PMOFF + k * PROWS + proff(ii) + i] = col[ii];
    }

    #pragma unroll
    for (int ii = 0; ii < D; ++ii) sL[ii][i] = col[ii];
    __syncthreads();

    // w_k[i] = sum_b invLc[i][b] * mu[k][b]
    {
        float s = 0.0f;
        #pragma unroll
        for (int b = 0; b < D; ++b) s = fmaf(sL[i][b], mu[k * D + b], s);
        ws[WOFF + k * D + i] = s;
    }
}

// ---------------------------------------------------------------------------
// setup2 (unchanged from round 5): pair constants from staged Lc.
// ---------------------------------------------------------------------------
#define SLC(kk, r, c) sLc2[(kk) * 1024 + (r) * 32 + (c)]

__global__ __launch_bounds__(64) void setup2_kernel(
    const float* __restrict__ mu, const float* __restrict__ weights,
    float* __restrict__ ws)
{
    __shared__ float sLc2[K * D * D];   // 32 KB
    __shared__ float sLogw[K];
    __shared__ float sCp[NPAIR];
    __shared__ float sCmax;
    const int tid = threadIdx.x;

    {
        const float4* src = (const float4*)(ws + LCOFF);
        float4* dst = (float4*)sLc2;
        for (int e = tid; e < K * D * D / 4; e += 64) dst[e] = src[e];
    }
    if (tid == 0) {
        float m = -INFINITY;
        for (int t = 0; t < K; ++t) m = fmaxf(m, weights[t]);
        float s = 0.0f;
        for (int t = 0; t < K; ++t) s += expf(weights[t] - m);
        const float lse = m + logf(s);
        for (int t = 0; t < K; ++t) sLogw[t] = weights[t] - lse;
    }
    __syncthreads();

    if (tid < NPAIR) {
        int tt = tid, pi = 0;
        while (tt >= (K - pi)) { tt -= (K - pi); ++pi; }
        const int pj = pi + tt;
        const float LOG2PI = 1.8378770664093453f;
        float sumlogS = 0.0f, logdetsig = 0.0f;
        #pragma unroll
        for (int r = 0; r < D; ++r) {
            const float di = SLC(pi, r, r), dj = SLC(pj, r, r);
            sumlogS += logf(di + dj);
            logdetsig -= logf(1.0f / di + 1.0f / dj);
        }
        float v[D];
        float quad_acc = 0.0f;
        #pragma unroll
        for (int r = 0; r < D; ++r) {
            const float d0 = mu[pi * D + r] - mu[pj * D + r];
            float s = d0;
            #pragma unroll
            for (int b = 0; b < r; ++b)
                s = fmaf(-(SLC(pi, r, b) + SLC(pj, r, b)), v[b], s);
            v[r] = s / (SLC(pi, r, r) + SLC(pj, r, r));
            quad_acc = fmaf(d0, v[r], quad_acc);
        }
        const float quad = -0.5f * quad_acc;
        float c = quad - 0.5f * sumlogS - (float)D * LOG2PI - 0.5f * logdetsig
                  + sLogw[pi] + sLogw[pj];
        if (pi < pj) c += 0.6931471805599453f;
        sCp[tid] = c;
    }
    __syncthreads();
    if (tid == 0) {
        float m = -INFINITY;
        for (int t = 0; t < NPAIR; ++t) m = fmaxf(m, sCp[t]);
        sCmax = m;
        ws[CMAXOFF] = m;
    }
    __syncthreads();
    if (tid < NPAIR)
        ws[C2OFF + tid] = (sCp[tid] - sCmax) * 1.4426950408889634f;
}

// ---------------------------------------------------------------------------
// main v3: M/w/c2 read as WAVE-UNIFORM scalar loads (s_load -> SGPR) straight
// from global; LDS only for the 16B reduction buffer. Requirements for the
// backend to scalarize: no divergent control flow anywhere (branchless clamp
// and masking only), uniform loop counters, const __restrict__ pointers.
// k-loop split in halves keeps live VGPRs ~200 (no spills at 2 waves/SIMD).
// ---------------------------------------------------------------------------
__global__ __launch_bounds__(256, 2) void main_kernel(
    const float* __restrict__ X, const float* __restrict__ cst,
    float* __restrict__ partials, int nsamp)
{
    __shared__ float sRed[4];
    const int tid = threadIdx.x;
    const int n = blockIdx.x * 256 + tid;
    const int m = (n < nsamp) ? n : 0;          // branchless clamp (cndmask)

    // per-lane x in registers
    v2f x[16];
    {
        const float4* Xv = (const float4*)(X + m * D);
        #pragma unroll
        for (int q = 0; q < 8; ++q) {
            const float4 t = Xv[q];
            x[2 * q]     = (v2f){t.x, t.y};
            x[2 * q + 1] = (v2f){t.z, t.w};
        }
    }

    v2f G2[NPAIR];
    #pragma unroll
    for (int t = 0; t < NPAIR; ++t) G2[t] = (v2f){0.0f, 0.0f};

    #pragma unroll 1
    for (int rh = 0; rh < 8; ++rh) {
        const int w4 = 4 * (rh + 1);                      // packed row width
        const float* grp = cst + 8 * rh * (rh + 1);       // +k*576 +rr*w4 +4*c4
        v2f yp[K][2];                                     // y rows 4rh..4rh+3

        #pragma unroll 1
        for (int kh = 0; kh < 2; ++kh) {                  // k in halves: VGPR cap
            v2f a[4][4];                                  // [k-sub][row] col-pairs
            #pragma unroll
            for (int ks = 0; ks < 4; ++ks) {
                const int k = 4 * kh + ks;
                const float4 wv = *(const float4*)(cst + WOFF + k * D + 4 * rh);
                a[ks][0] = (v2f){-wv.x, 0.0f};
                a[ks][1] = (v2f){-wv.y, 0.0f};
                a[ks][2] = (v2f){-wv.z, 0.0f};
                a[ks][3] = (v2f){-wv.w, 0.0f};
            }
            #pragma unroll 1
            for (int c4 = 0; c4 <= rh; ++c4) {
                const float* col = grp + 4 * c4 + kh * 4 * PROWS;
                #pragma unroll
                for (int ks = 0; ks < 4; ++ks) {
                    const float* pk_ = col + ks * PROWS;
                    #pragma unroll
                    for (int rr = 0; rr < 4; ++rr) {
                        const float4 m4 = *(const float4*)(pk_ + rr * w4);  // uniform -> s_load
                        a[ks][rr] = __builtin_elementwise_fma(
                            (v2f){m4.x, m4.y}, x[2 * c4], a[ks][rr]);
                        a[ks][rr] = __builtin_elementwise_fma(
                            (v2f){m4.z, m4.w}, x[2 * c4 + 1], a[ks][rr]);
                    }
                }
            }
            #pragma unroll
            for (int ks = 0; ks < 4; ++ks) {
                yp[4 * kh + ks][0] = (v2f){a[ks][0].x + a[ks][0].y,
                                           a[ks][1].x + a[ks][1].y};
                yp[4 * kh + ks][1] = (v2f){a[ks][2].x + a[ks][2].y,
                                           a[ks][3].x + a[ks][3].y};
            }
        }

        #pragma unroll
        for (int pi = 0; pi < K; ++pi)
            #pragma unroll
            for (int pj = pi; pj < K; ++pj) {
                v2f g = G2[gidx(pi, pj)];
                g = __builtin_elementwise_fma(yp[pi][0], yp[pj][0], g);
                g = __builtin_elementwise_fma(yp[pi][1], yp[pj][1], g);
                G2[gidx(pi, pj)] = g;
            }
    }

    float G[NPAIR];
    #pragma unroll
    for (int t = 0; t < NPAIR; ++t) G[t] = G2[t].x + G2[t].y;

    // 36-term exp sum; q >= 0, c2 <= 0 -> exp2 arg <= 0 (no overflow)
    float acc = 0.0f;
    const float NH = -0.72134752044448170f;   // -0.5*log2(e)
    #pragma unroll
    for (int pi = 0; pi < K; ++pi)
        #pragma unroll
        for (int pj = pi; pj < K; ++pj) {
            const float q = fmaf(2.0f, G[gidx(pi, pj)],
                                 G[gidx(pi, pi)] + G[gidx(pj, pj)]);
            acc += exp2f(fmaf(NH, q, cst[C2OFF + gidx(pi, pj)]));   // uniform c2
        }
    acc = (n < nsamp) ? acc : 0.0f;           // branchless mask

    #pragma unroll
    for (int s = 1; s < 64; s <<= 1) acc += __shfl_xor(acc, s, 64);
    if ((tid & 63) == 0) sRed[tid >> 6] = acc;
    __syncthreads();
    if (tid == 0)
        partials[blockIdx.x] = sRed[0] + sRed[1] + sRed[2] + sRed[3];
}

__global__ __launch_bounds__(256) void finish_kernel(
    const float* __restrict__ partials, const float* __restrict__ ws,
    float* __restrict__ out, int nblk)
{
    __shared__ float sRed[4];
    const int tid = threadIdx.x;
    float acc = 0.0f;
    for (int e = tid; e < nblk; e += 256) acc += partials[e];
    #pragma unroll
    for (int s = 1; s < 64; s <<= 1) acc += __shfl_xor(acc, s, 64);
    if ((tid & 63) == 0) sRed[tid >> 6] = acc;
    __syncthreads();
    if (tid == 0) out[0] = ws[CMAXOFF] + logf(sRed[0] + sRed[1] + sRed[2] + sRed[3]);
}

extern "C" void kernel_launch(void* const* d_in, const int* in_sizes, int n_in,
                              void* d_out, int out_size, void* d_ws, size_t ws_size,
                              hipStream_t stream) {
    const float* X = (const float*)d_in[0];
    const float* mu = (const float*)d_in[1];
    const float* L = (const float*)d_in[2];
    const float* w = (const float*)d_in[3];
    float* wsf = (float*)d_ws;
    float* out = (float*)d_out;

    const int nsamp = in_sizes[0] / D;
    const int nblk = (nsamp + 255) / 256;

    setup1_kernel<<<K, 64, 0, stream>>>(mu, L, wsf);
    setup2_kernel<<<1, 64, 0, stream>>>(mu, w, wsf);
    main_kernel<<<nblk, 256, 0, stream>>>(X, wsf, wsf + PARTOFF, nsamp);
    finish_kernel<<<1, 256, 0, stream>>>(wsf + PARTOFF, wsf, out, nblk);
}

// Round 7
// 173.781 us; speedup vs baseline: 1.2379x; 1.2379x over previous
//
#include <hip/hip_runtime.h>

// Problem constants
#define D 32
#define K 8
#define NPAIR 36
#define PROWS 576              // packed (4-padded triangular) floats per matrix

// ws layout (float offsets)
#define PMOFF 0                // packed invLc, 8 x 576
#define WOFF 4608              // w_k = invLc_k mu_k, 8 x 32
#define C2OFF 4864             // (c'_t - cmax) * log2(e), 36
#define CMAXOFF 4900
#define LCOFF 4928             // Lc (cholesky factors), 8 x 32 x 32, upper zeroed
#define PARTOFF 13120          // per-block partial sums (<=1024)

typedef float v2f __attribute__((ext_vector_type(2)));

__host__ __device__ constexpr int gidx(int i, int j) {  // i<=j packed pair index
    return i * 8 + j - i * (i + 1) / 2;
}
__host__ __device__ constexpr int proff(int r) {        // packed row offset
    return 4 * (r / 4 + 1) * (2 * (r / 4) + (r % 4));
}

// ---------------------------------------------------------------------------
// setup1 (unchanged, verified): one 64-thread block per cluster; at most one
// 32-float register array live per phase (no spills).
// ---------------------------------------------------------------------------
__global__ __launch_bounds__(64) void setup1_kernel(
    const float* __restrict__ mu, const float* __restrict__ L,
    float* __restrict__ ws)
{
    __shared__ float sL[D][D + 1];
    __shared__ float sLc[D][D + 1];
    const int k = blockIdx.x;
    const int tid = threadIdx.x;
    const int i = tid & 31;

    for (int e = tid; e < D * D; e += 64) sL[e >> 5][e & 31] = L[k * D * D + e];
    __syncthreads();

    float a[D];
    {
        float l[D];
        #pragma unroll
        for (int b = 0; b < D; ++b) l[b] = sL[i][b];
        #pragma unroll
        for (int c = 0; c < D; ++c) {
            float s = (i == c) ? 1.0f : 0.0f;
            #pragma unroll
            for (int b = 0; b < D; ++b) s = fmaf(l[b], sL[c][b], s);
            a[c] = s;
        }
    }
    __syncthreads();

    #pragma unroll
    for (int j = 0; j < D; ++j) {
        if (i == j) {
            float s = a[j];
            #pragma unroll
            for (int b = 0; b < j; ++b) s = fmaf(-a[b], a[b], s);
            const float d = sqrtf(s);
            a[j] = d;
            #pragma unroll
            for (int b = 0; b < j; ++b) sLc[j][b] = a[b];
            sLc[j][j] = d;
        }
        __syncthreads();
        if (i > j) {
            float s = a[j];
            #pragma unroll
            for (int b = 0; b < j; ++b) s = fmaf(-a[b], sLc[j][b], s);
            a[j] = s / sLc[j][j];
        }
    }
    __syncthreads();

    for (int e = tid; e < D * D; e += 64) {
        const int r = e >> 5, c = e & 31;
        ws[LCOFF + k * D * D + e] = (c <= r) ? sLc[r][c] : 0.0f;
    }

    float col[D];
    #pragma unroll
    for (int ii = 0; ii < D; ++ii) {
        float s = (ii == i) ? 1.0f : 0.0f;
        #pragma unroll
        for (int b = 0; b < ii; ++b) {
            const float m = (b >= i) ? sLc[ii][b] : 0.0f;
            s = fmaf(-m, col[b], s);
        }
        col[ii] = s / sLc[ii][ii];
    }

    #pragma unroll
    for (int ii = 0; ii < D; ++ii) {
        const int w4 = 4 * (ii / 4 + 1);
        if (i < w4) ws[PMOFF + k * PROWS + proff(ii) + i] = col[ii];
    }

    #pragma unroll
    for (int ii = 0; ii < D; ++ii) sL[ii][i] = col[ii];
    __syncthreads();

    {
        float s = 0.0f;
        #pragma unroll
        for (int b = 0; b < D; ++b) s = fmaf(sL[i][b], mu[k * D + b], s);
        ws[WOFF + k * D + i] = s;
    }
}

// ---------------------------------------------------------------------------
// setup2 (unchanged): pair constants from staged Lc.
// ---------------------------------------------------------------------------
#define SLC(kk, r, c) sLc2[(kk) * 1024 + (r) * 32 + (c)]

__global__ __launch_bounds__(64) void setup2_kernel(
    const float* __restrict__ mu, const float* __restrict__ weights,
    float* __restrict__ ws)
{
    __shared__ float sLc2[K * D * D];
    __shared__ float sLogw[K];
    __shared__ float sCp[NPAIR];
    __shared__ float sCmax;
    const int tid = threadIdx.x;

    {
        const float4* src = (const float4*)(ws + LCOFF);
        float4* dst = (float4*)sLc2;
        for (int e = tid; e < K * D * D / 4; e += 64) dst[e] = src[e];
    }
    if (tid == 0) {
        float m = -INFINITY;
        for (int t = 0; t < K; ++t) m = fmaxf(m, weights[t]);
        float s = 0.0f;
        for (int t = 0; t < K; ++t) s += expf(weights[t] - m);
        const float lse = m + logf(s);
        for (int t = 0; t < K; ++t) sLogw[t] = weights[t] - lse;
    }
    __syncthreads();

    if (tid < NPAIR) {
        int tt = tid, pi = 0;
        while (tt >= (K - pi)) { tt -= (K - pi); ++pi; }
        const int pj = pi + tt;
        const float LOG2PI = 1.8378770664093453f;
        float sumlogS = 0.0f, logdetsig = 0.0f;
        #pragma unroll
        for (int r = 0; r < D; ++r) {
            const float di = SLC(pi, r, r), dj = SLC(pj, r, r);
            sumlogS += logf(di + dj);
            logdetsig -= logf(1.0f / di + 1.0f / dj);
        }
        float v[D];
        float quad_acc = 0.0f;
        #pragma unroll
        for (int r = 0; r < D; ++r) {
            const float d0 = mu[pi * D + r] - mu[pj * D + r];
            float s = d0;
            #pragma unroll
            for (int b = 0; b < r; ++b)
                s = fmaf(-(SLC(pi, r, b) + SLC(pj, r, b)), v[b], s);
            v[r] = s / (SLC(pi, r, r) + SLC(pj, r, r));
            quad_acc = fmaf(d0, v[r], quad_acc);
        }
        const float quad = -0.5f * quad_acc;
        float c = quad - 0.5f * sumlogS - (float)D * LOG2PI - 0.5f * logdetsig
                  + sLogw[pi] + sLogw[pj];
        if (pi < pj) c += 0.6931471805599453f;
        sCp[tid] = c;
    }
    __syncthreads();
    if (tid == 0) {
        float m = -INFINITY;
        for (int t = 0; t < NPAIR; ++t) m = fmaxf(m, sCp[t]);
        sCmax = m;
        ws[CMAXOFF] = m;
    }
    __syncthreads();
    if (tid < NPAIR)
        ws[C2OFF + tid] = (sCp[tid] - sCmax) * 1.4426950408889634f;
}

// ---------------------------------------------------------------------------
// main v4: S=2 samples/thread, v2f = {sample0, sample1} throughout.
// M split by cluster half: k=0..3 from LDS (9.2 KB broadcast), k=4..7 from
// global wave-uniform reads (K$/L1-resident, fully unrolled for deep
// prefetch). Row-wise Gram keeps live VGPRs ~190. grid=256 -> 1 block/CU,
// 4 waves/CU; LDS pipe sees only 576 b128 per wave per 128 samples.
// ---------------------------------------------------------------------------
__global__ __launch_bounds__(256, 1) void main_kernel(
    const float* __restrict__ X, const float* __restrict__ cst,
    float* __restrict__ partials, int nsamp)
{
    __shared__ __align__(16) float sM[4 * PROWS];   // packed invLc, k=0..3
    __shared__ __align__(16) float sW[K * D];
    __shared__ float sC2[NPAIR];
    __shared__ float sRed[4];
    const int tid = threadIdx.x;

    const int n0 = blockIdx.x * 512 + tid;
    const int n1 = n0 + 256;
    const int m0 = (n0 < nsamp) ? n0 : 0;     // branchless clamps
    const int m1 = (n1 < nsamp) ? n1 : 0;

    // x for both samples, packed sample-wise: xp[c] = {x0[c], x1[c]}
    v2f xp[D];
    {
        const float4* Xv0 = (const float4*)(X + m0 * D);
        const float4* Xv1 = (const float4*)(X + m1 * D);
        #pragma unroll
        for (int q = 0; q < 8; ++q) {
            const float4 t0 = Xv0[q];
            const float4 t1 = Xv1[q];
            xp[4 * q + 0] = (v2f){t0.x, t1.x};
            xp[4 * q + 1] = (v2f){t0.y, t1.y};
            xp[4 * q + 2] = (v2f){t0.z, t1.z};
            xp[4 * q + 3] = (v2f){t0.w, t1.w};
        }
    }

    {   // stage k=0..3 packed M + w + c2 into LDS
        const float4* src = (const float4*)cst;
        float4* dst = (float4*)sM;
        for (int e = tid; e < PROWS; e += 256) dst[e] = src[e];          // 4*576/4
        const float4* srcw = (const float4*)(cst + WOFF);
        float4* dstw = (float4*)sW;
        if (tid < K * D / 4) dstw[tid] = srcw[tid];
        if (tid < NPAIR) sC2[tid] = cst[C2OFF + tid];
    }
    __syncthreads();

    v2f G2[NPAIR];
    #pragma unroll
    for (int t = 0; t < NPAIR; ++t) G2[t] = (v2f){0.0f, 0.0f};

    #pragma unroll
    for (int rh = 0; rh < 8; ++rh) {
        #pragma unroll
        for (int rr = 0; rr < 4; ++rr) {
            const int r = 4 * rh + rr;
            v2f y2[K];
            // k = 0..3: M rows from LDS (wave-uniform broadcast)
            #pragma unroll
            for (int k = 0; k < 4; ++k) {
                const float wv = sW[k * D + r];
                v2f a = (v2f){-wv, -wv};
                const float* Mr = sM + k * PROWS + proff(r);
                #pragma unroll
                for (int c4 = 0; c4 <= rh; ++c4) {
                    const float4 m4 = *(const float4*)(Mr + 4 * c4);
                    a = __builtin_elementwise_fma((v2f){m4.x, m4.x}, xp[4 * c4 + 0], a);
                    a = __builtin_elementwise_fma((v2f){m4.y, m4.y}, xp[4 * c4 + 1], a);
                    a = __builtin_elementwise_fma((v2f){m4.z, m4.z}, xp[4 * c4 + 2], a);
                    a = __builtin_elementwise_fma((v2f){m4.w, m4.w}, xp[4 * c4 + 3], a);
                }
                y2[k] = a;
            }
            // k = 4..7: M rows from global (wave-uniform, K$/L1-resident)
            #pragma unroll
            for (int k = 4; k < 8; ++k) {
                const float wv = sW[k * D + r];
                v2f a = (v2f){-wv, -wv};
                const float* Mr = cst + k * PROWS + proff(r);
                #pragma unroll
                for (int c4 = 0; c4 <= rh; ++c4) {
                    const float4 m4 = *(const float4*)(Mr + 4 * c4);
                    a = __builtin_elementwise_fma((v2f){m4.x, m4.x}, xp[4 * c4 + 0], a);
                    a = __builtin_elementwise_fma((v2f){m4.y, m4.y}, xp[4 * c4 + 1], a);
                    a = __builtin_elementwise_fma((v2f){m4.z, m4.z}, xp[4 * c4 + 2], a);
                    a = __builtin_elementwise_fma((v2f){m4.w, m4.w}, xp[4 * c4 + 3], a);
                }
                y2[k] = a;
            }
            // row-wise Gram update: G_ij += y_i * y_j (componentwise per sample)
            #pragma unroll
            for (int pi = 0; pi < K; ++pi)
                #pragma unroll
                for (int pj = pi; pj < K; ++pj)
                    G2[gidx(pi, pj)] = __builtin_elementwise_fma(
                        y2[pi], y2[pj], G2[gidx(pi, pj)]);
        }
    }

    // 36-term exp sum for both samples; q >= 0, c2 <= 0 -> exp2 arg <= 0
    v2f acc2 = (v2f){0.0f, 0.0f};
    const float NH = -0.72134752044448170f;   // -0.5*log2(e)
    #pragma unroll
    for (int pi = 0; pi < K; ++pi)
        #pragma unroll
        for (int pj = pi; pj < K; ++pj) {
            const v2f q2 = __builtin_elementwise_fma(
                (v2f){2.0f, 2.0f}, G2[gidx(pi, pj)],
                G2[gidx(pi, pi)] + G2[gidx(pj, pj)]);
            const float c = sC2[gidx(pi, pj)];
            const v2f e2 = __builtin_elementwise_fma((v2f){NH, NH}, q2, (v2f){c, c});
            acc2.x += exp2f(e2.x);
            acc2.y += exp2f(e2.y);
        }
    float acc = ((n0 < nsamp) ? acc2.x : 0.0f) + ((n1 < nsamp) ? acc2.y : 0.0f);

    #pragma unroll
    for (int s = 1; s < 64; s <<= 1) acc += __shfl_xor(acc, s, 64);
    if ((tid & 63) == 0) sRed[tid >> 6] = acc;
    __syncthreads();
    if (tid == 0)
        partials[blockIdx.x] = sRed[0] + sRed[1] + sRed[2] + sRed[3];
}

__global__ __launch_bounds__(256) void finish_kernel(
    const float* __restrict__ partials, const float* __restrict__ ws,
    float* __restrict__ out, int nblk)
{
    __shared__ float sRed[4];
    const int tid = threadIdx.x;
    float acc = 0.0f;
    for (int e = tid; e < nblk; e += 256) acc += partials[e];
    #pragma unroll
    for (int s = 1; s < 64; s <<= 1) acc += __shfl_xor(acc, s, 64);
    if ((tid & 63) == 0) sRed[tid >> 6] = acc;
    __syncthreads();
    if (tid == 0) out[0] = ws[CMAXOFF] + logf(sRed[0] + sRed[1] + sRed[2] + sRed[3]);
}

extern "C" void kernel_launch(void* const* d_in, const int* in_sizes, int n_in,
                              void* d_out, int out_size, void* d_ws, size_t ws_size,
                              hipStream_t stream) {
    const float* X = (const float*)d_in[0];
    const float* mu = (const float*)d_in[1];
    const float* L = (const float*)d_in[2];
    const float* w = (const float*)d_in[3];
    float* wsf = (float*)d_ws;
    float* out = (float*)d_out;

    const int nsamp = in_sizes[0] / D;
    const int nblk = (nsamp + 511) / 512;   // S=2, 256 threads -> 1 block/CU

    setup1_kernel<<<K, 64, 0, stream>>>(mu, L, wsf);
    setup2_kernel<<<1, 64, 0, stream>>>(mu, w, wsf);
    main_kernel<<<nblk, 256, 0, stream>>>(X, wsf, wsf + PARTOFF, nsamp);
    finish_kernel<<<1, 256, 0, stream>>>(wsf + PARTOFF, wsf, out, nblk);
}

// Round 8
// 163.431 us; speedup vs baseline: 1.3163x; 1.0633x over previous
//
#include <hip/hip_runtime.h>

// Problem constants
#define D 32
#define K 8
#define NPAIR 36
#define PROWS 576              // packed (4-padded triangular) floats per matrix

// ws layout (float offsets)
#define PMOFF 0                // packed invLc, 8 x 576
#define WOFF 4608              // w_k = invLc_k mu_k, 8 x 32
#define C2OFF 4864             // (c'_t - cmax) * log2(e), 36
#define CMAXOFF 4900
#define LCOFF 4928             // Lc (cholesky factors), 8 x 32 x 32, upper zeroed
#define PARTOFF 13120          // per-block partial sums (<=1024)

typedef float v2f __attribute__((ext_vector_type(2)));

__host__ __device__ constexpr int gidx(int i, int j) {  // i<=j packed pair index
    return i * 8 + j - i * (i + 1) / 2;
}
__host__ __device__ constexpr int proff(int r) {        // packed row offset
    return 4 * (r / 4 + 1) * (2 * (r / 4) + (r % 4));
}

// ---------------------------------------------------------------------------
// setup1 v3: one 64-thread block per cluster. The only register array is
// lrow[32] (Cholesky). The invLc column solve keeps its state in LDS
// (thread j reads sI[b][j], written by itself at step b; zero above diagonal
// by construction -> no predication, no col[] array, no spills).
// ---------------------------------------------------------------------------
__global__ __launch_bounds__(64) void setup1_kernel(
    const float* __restrict__ mu, const float* __restrict__ L,
    float* __restrict__ ws)
{
    __shared__ float sA[D][D + 1];    // A = L L^T + I
    __shared__ float sLc[D][D + 1];   // published Cholesky rows
    __shared__ float sI[D][D + 1];    // L staging, then invLc columns
    const int k = blockIdx.x;
    const int tid = threadIdx.x;
    const int i = tid & 31;

    // stage L into sI (temporary use)
    for (int e = tid; e < D * D; e += 64) sI[e >> 5][e & 31] = L[k * D * D + e];
    __syncthreads();

    // Phase A (cooperative, no reg arrays): A[a][c] = <L_a, L_c> + (a==c)
    for (int e = tid; e < D * D; e += 64) {
        const int a = e >> 5, c = e & 31;
        float s = (a == c) ? 1.0f : 0.0f;
        #pragma unroll
        for (int b = 0; b < D; ++b) s = fmaf(sI[a][b], sI[c][b], s);
        sA[a][c] = s;
    }
    __syncthreads();

    // Phase B: left-looking Cholesky, thread-per-row, lrow[] only live array
    float lrow[D];
    #pragma unroll
    for (int j = 0; j < D; ++j) {
        if (i == j) {
            float s = sA[j][j];
            #pragma unroll
            for (int b = 0; b < j; ++b) s = fmaf(-lrow[b], lrow[b], s);
            const float d = sqrtf(s);
            lrow[j] = d;
            #pragma unroll
            for (int b = 0; b < j; ++b) sLc[j][b] = lrow[b];
            sLc[j][j] = d;
        }
        __syncthreads();
        if (i > j) {
            float s = sA[i][j];
            #pragma unroll
            for (int b = 0; b < j; ++b) s = fmaf(-lrow[b], sLc[j][b], s);
            lrow[j] = s / sLc[j][j];
        }
    }
    __syncthreads();   // all Lc rows published; sI (L copy) now dead

    // Lc rows to ws for setup2 (upper zeroed; coalesced)
    for (int e = tid; e < D * D; e += 64) {
        const int r = e >> 5, c = e & 31;
        ws[LCOFF + k * D * D + e] = (c <= r) ? sLc[r][c] : 0.0f;
    }

    // Phase C: thread j = i solves invLc column j with state in LDS.
    // sI[b][j] = 0 for b < j falls out naturally (s stays 0); reads of
    // sLc[ii][b] are lane-uniform broadcasts; sI[b][j] banks = (b+j)%32.
    {
        const int j = i;
        #pragma unroll
        for (int ii = 0; ii < D; ++ii) {
            float s = (ii == j) ? 1.0f : 0.0f;
            #pragma unroll
            for (int b = 0; b < ii; ++b) s = fmaf(-sLc[ii][b], sI[b][j], s);
            const float cii = s / sLc[ii][ii];
            sI[ii][j] = cii;
            const int w4 = 4 * (ii / 4 + 1);
            if (j < w4) ws[PMOFF + k * PROWS + proff(ii) + j] = cii;
        }
    }
    __syncthreads();

    // Phase D: w_k[i] = sum_b invLc[i][b] * mu[k][b] (mu wave-uniform)
    {
        float s = 0.0f;
        #pragma unroll
        for (int b = 0; b < D; ++b) s = fmaf(sI[i][b], mu[k * D + b], s);
        ws[WOFF + k * D + i] = s;
    }
}

// ---------------------------------------------------------------------------
// setup2 (unchanged): pair constants from staged Lc.
// ---------------------------------------------------------------------------
#define SLC(kk, r, c) sLc2[(kk) * 1024 + (r) * 32 + (c)]

__global__ __launch_bounds__(64) void setup2_kernel(
    const float* __restrict__ mu, const float* __restrict__ weights,
    float* __restrict__ ws)
{
    __shared__ float sLc2[K * D * D];
    __shared__ float sLogw[K];
    __shared__ float sCp[NPAIR];
    __shared__ float sCmax;
    const int tid = threadIdx.x;

    {
        const float4* src = (const float4*)(ws + LCOFF);
        float4* dst = (float4*)sLc2;
        for (int e = tid; e < K * D * D / 4; e += 64) dst[e] = src[e];
    }
    if (tid == 0) {
        float m = -INFINITY;
        for (int t = 0; t < K; ++t) m = fmaxf(m, weights[t]);
        float s = 0.0f;
        for (int t = 0; t < K; ++t) s += expf(weights[t] - m);
        const float lse = m + logf(s);
        for (int t = 0; t < K; ++t) sLogw[t] = weights[t] - lse;
    }
    __syncthreads();

    if (tid < NPAIR) {
        int tt = tid, pi = 0;
        while (tt >= (K - pi)) { tt -= (K - pi); ++pi; }
        const int pj = pi + tt;
        const float LOG2PI = 1.8378770664093453f;
        float sumlogS = 0.0f, logdetsig = 0.0f;
        #pragma unroll
        for (int r = 0; r < D; ++r) {
            const float di = SLC(pi, r, r), dj = SLC(pj, r, r);
            sumlogS += logf(di + dj);
            logdetsig -= logf(1.0f / di + 1.0f / dj);
        }
        float v[D];
        float quad_acc = 0.0f;
        #pragma unroll
        for (int r = 0; r < D; ++r) {
            const float d0 = mu[pi * D + r] - mu[pj * D + r];
            float s = d0;
            #pragma unroll
            for (int b = 0; b < r; ++b)
                s = fmaf(-(SLC(pi, r, b) + SLC(pj, r, b)), v[b], s);
            v[r] = s / (SLC(pi, r, r) + SLC(pj, r, r));
            quad_acc = fmaf(d0, v[r], quad_acc);
        }
        const float quad = -0.5f * quad_acc;
        float c = quad - 0.5f * sumlogS - (float)D * LOG2PI - 0.5f * logdetsig
                  + sLogw[pi] + sLogw[pj];
        if (pi < pj) c += 0.6931471805599453f;
        sCp[tid] = c;
    }
    __syncthreads();
    if (tid == 0) {
        float m = -INFINITY;
        for (int t = 0; t < NPAIR; ++t) m = fmaxf(m, sCp[t]);
        sCmax = m;
        ws[CMAXOFF] = m;
    }
    __syncthreads();
    if (tid < NPAIR)
        ws[C2OFF + tid] = (sCp[tid] - sCmax) * 1.4426950408889634f;
}

// ---------------------------------------------------------------------------
// main v5: S=2 samples/thread, v2f = {sample0, sample1}; ALL of packed M in
// LDS (18.4 KB) -- broadcast b128 reads only (R7's global half stalled).
// 1152 ds_read_b128 per wave per 128 samples; full unroll feeds the pipe.
// ---------------------------------------------------------------------------
__global__ __launch_bounds__(256, 1) void main_kernel(
    const float* __restrict__ X, const float* __restrict__ cst,
    float* __restrict__ partials, int nsamp)
{
    __shared__ __align__(16) float sM[K * PROWS];   // 18.4 KB packed invLc
    __shared__ __align__(16) float sW[K * D];
    __shared__ float sC2[NPAIR];
    __shared__ float sRed[4];
    const int tid = threadIdx.x;

    const int n0 = blockIdx.x * 512 + tid;
    const int n1 = n0 + 256;
    const int m0 = (n0 < nsamp) ? n0 : 0;     // branchless clamps
    const int m1 = (n1 < nsamp) ? n1 : 0;

    // x for both samples, packed sample-wise: xp[c] = {x0[c], x1[c]}
    v2f xp[D];
    {
        const float4* Xv0 = (const float4*)(X + m0 * D);
        const float4* Xv1 = (const float4*)(X + m1 * D);
        #pragma unroll
        for (int q = 0; q < 8; ++q) {
            const float4 t0 = Xv0[q];
            const float4 t1 = Xv1[q];
            xp[4 * q + 0] = (v2f){t0.x, t1.x};
            xp[4 * q + 1] = (v2f){t0.y, t1.y};
            xp[4 * q + 2] = (v2f){t0.z, t1.z};
            xp[4 * q + 3] = (v2f){t0.w, t1.w};
        }
    }

    {   // stage all packed M + w + c2 into LDS
        const float4* src = (const float4*)cst;
        float4* dst = (float4*)sM;
        for (int e = tid; e < K * PROWS / 4; e += 256) dst[e] = src[e];
        const float4* srcw = (const float4*)(cst + WOFF);
        float4* dstw = (float4*)sW;
        if (tid < K * D / 4) dstw[tid] = srcw[tid];
        if (tid < NPAIR) sC2[tid] = cst[C2OFF + tid];
    }
    __syncthreads();

    v2f G2[NPAIR];
    #pragma unroll
    for (int t = 0; t < NPAIR; ++t) G2[t] = (v2f){0.0f, 0.0f};

    #pragma unroll
    for (int rh = 0; rh < 8; ++rh) {
        #pragma unroll
        for (int rr = 0; rr < 4; ++rr) {
            const int r = 4 * rh + rr;
            v2f y2[K];
            #pragma unroll
            for (int k = 0; k < K; ++k) {
                const float wv = sW[k * D + r];
                v2f a = (v2f){-wv, -wv};
                const float* Mr = sM + k * PROWS + proff(r);
                #pragma unroll
                for (int c4 = 0; c4 <= rh; ++c4) {
                    const float4 m4 = *(const float4*)(Mr + 4 * c4);
                    a = __builtin_elementwise_fma((v2f){m4.x, m4.x}, xp[4 * c4 + 0], a);
                    a = __builtin_elementwise_fma((v2f){m4.y, m4.y}, xp[4 * c4 + 1], a);
                    a = __builtin_elementwise_fma((v2f){m4.z, m4.z}, xp[4 * c4 + 2], a);
                    a = __builtin_elementwise_fma((v2f){m4.w, m4.w}, xp[4 * c4 + 3], a);
                }
                y2[k] = a;
            }
            // Gram update: G_ij += y_i * y_j (componentwise per sample)
            #pragma unroll
            for (int pi = 0; pi < K; ++pi)
                #pragma unroll
                for (int pj = pi; pj < K; ++pj)
                    G2[gidx(pi, pj)] = __builtin_elementwise_fma(
                        y2[pi], y2[pj], G2[gidx(pi, pj)]);
        }
    }

    // 36-term exp sum for both samples; q >= 0, c2 <= 0 -> exp2 arg <= 0
    v2f acc2 = (v2f){0.0f, 0.0f};
    const float NH = -0.72134752044448170f;   // -0.5*log2(e)
    #pragma unroll
    for (int pi = 0; pi < K; ++pi)
        #pragma unroll
        for (int pj = pi; pj < K; ++pj) {
            const v2f q2 = __builtin_elementwise_fma(
                (v2f){2.0f, 2.0f}, G2[gidx(pi, pj)],
                G2[gidx(pi, pi)] + G2[gidx(pj, pj)]);
            const float c = sC2[gidx(pi, pj)];
            const v2f e2 = __builtin_elementwise_fma((v2f){NH, NH}, q2, (v2f){c, c});
            acc2.x += exp2f(e2.x);
            acc2.y += exp2f(e2.y);
        }
    float acc = ((n0 < nsamp) ? acc2.x : 0.0f) + ((n1 < nsamp) ? acc2.y : 0.0f);

    #pragma unroll
    for (int s = 1; s < 64; s <<= 1) acc += __shfl_xor(acc, s, 64);
    if ((tid & 63) == 0) sRed[tid >> 6] = acc;
    __syncthreads();
    if (tid == 0)
        partials[blockIdx.x] = sRed[0] + sRed[1] + sRed[2] + sRed[3];
}

__global__ __launch_bounds__(256) void finish_kernel(
    const float* __restrict__ partials, const float* __restrict__ ws,
    float* __restrict__ out, int nblk)
{
    __shared__ float sRed[4];
    const int tid = threadIdx.x;
    float acc = 0.0f;
    for (int e = tid; e < nblk; e += 256) acc += partials[e];
    #pragma unroll
    for (int s = 1; s < 64; s <<= 1) acc += __shfl_xor(acc, s, 64);
    if ((tid & 63) == 0) sRed[tid >> 6] = acc;
    __syncthreads();
    if (tid == 0) out[0] = ws[CMAXOFF] + logf(sRed[0] + sRed[1] + sRed[2] + sRed[3]);
}

extern "C" void kernel_launch(void* const* d_in, const int* in_sizes, int n_in,
                              void* d_out, int out_size, void* d_ws, size_t ws_size,
                              hipStream_t stream) {
    const float* X = (const float*)d_in[0];
    const float* mu = (const float*)d_in[1];
    const float* L = (const float*)d_in[2];
    const float* w = (const float*)d_in[3];
    float* wsf = (float*)d_ws;
    float* out = (float*)d_out;

    const int nsamp = in_sizes[0] / D;
    const int nblk = (nsamp + 511) / 512;   // S=2, 256 threads

    setup1_kernel<<<K, 64, 0, stream>>>(mu, L, wsf);
    setup2_kernel<<<1, 64, 0, stream>>>(mu, w, wsf);
    main_kernel<<<nblk, 256, 0, stream>>>(X, wsf, wsf + PARTOFF, nsamp);
    finish_kernel<<<1, 256, 0, stream>>>(wsf + PARTOFF, wsf, out, nblk);
}